// Round 1
// 285.518 us; speedup vs baseline: 1.1070x; 1.1070x over previous
//
#include <hip/hip_runtime.h>
#include <hip/hip_bf16.h>
#include <stdint.h>

#define N 4096
#define BM 128
#define BN 128
#define BK8 128    // fp8 K-tile (gemm_sym)
// gemm_pv 8-phase geometry:
#define PM 256
#define PN 256
#define PK 64

typedef __hip_bfloat16 bf16;
typedef __attribute__((ext_vector_type(8))) __bf16 bfrag;   // 8 bf16 (MFMA A/B operand)
typedef __attribute__((ext_vector_type(4))) float floatx4;  // MFMA C/D operand
typedef __attribute__((ext_vector_type(8))) int i32x8;      // 32 fp8 (f8f6f4 A/B operand)
typedef __attribute__((ext_vector_type(4))) int i32x4;

// ---------------------------------------------------------------------------
// async global -> LDS, 16B per lane (global_load_lds_dwordx4)
// ---------------------------------------------------------------------------
__device__ __forceinline__ void gld_lds16(const void* g, void* l) {
    __builtin_amdgcn_global_load_lds(
        (const __attribute__((address_space(1))) void*)g,
        (__attribute__((address_space(3))) void*)l, 16, 0, 0);
}

__device__ __forceinline__ unsigned short f2bf(float x) {
    __hip_bfloat16 h = __float2bfloat16(x);
    return *(unsigned short*)&h;
}

// ---------------------------------------------------------------------------
// Kernel 1: xb = bf16(in * 1/64)  (scaled, for gemm_pv's B operand)
//           x8 = fp8_e4m3(in)     (UNSCALED -- full e4m3 relative precision;
//                                  the 1/4096 is applied exactly via the MFMA
//                                  e8m0 scale operands, 2^-6 per operand)
// blocks 0..15 also zero rowsum (replaces the memset dispatch).
// ---------------------------------------------------------------------------
__global__ __launch_bounds__(256) void cvt_scale(const float* __restrict__ in,
                                                 unsigned short* __restrict__ xb,
                                                 uint8_t* __restrict__ x8,
                                                 float* __restrict__ rowsum) {
    if (blockIdx.x < 16) rowsum[blockIdx.x * 256 + threadIdx.x] = 0.f;
    const long i = ((long)blockIdx.x * 256 + threadIdx.x) * 8;
    float4 a = *(const float4*)(in + i);
    float4 b = *(const float4*)(in + i + 4);
    const float sc = 0.015625f;  // 1/64 = 1/sqrt(4096)
    float v[8] = {a.x, a.y, a.z, a.w, b.x, b.y, b.z, b.w};
    alignas(16) unsigned short r[8];
#pragma unroll
    for (int k = 0; k < 8; ++k) r[k] = f2bf(v[k] * sc);
    *(uint4*)(xb + i) = *(const uint4*)r;

    int p0 = __builtin_amdgcn_cvt_pk_fp8_f32(v[0], v[1], 0, false);
    p0     = __builtin_amdgcn_cvt_pk_fp8_f32(v[2], v[3], p0, true);
    int p1 = __builtin_amdgcn_cvt_pk_fp8_f32(v[4], v[5], 0, false);
    p1     = __builtin_amdgcn_cvt_pk_fp8_f32(v[6], v[7], p1, true);
    int2 pk; pk.x = p0; pk.y = p1;
    *(int2*)(x8 + i) = pk;
}

// ---------------------------------------------------------------------------
// Kernel 2 (gemm_sym): E = exp(mask(x x^T)), triangular 528-block grid,
// 512 threads (8 waves, 2x4 wave grid, 64x32 wave tile).  fp8 e4m3 at
// BK=128 via mfma_scale_f32_16x16x128_f8f6f4 (e8m0 scales 2^-6 each ->
// exact 1/4096 score scale in hardware).  Unchanged from R5 (verified).
// ---------------------------------------------------------------------------
__global__ __launch_bounds__(512) void gemm_sym(const uint8_t* __restrict__ X8,
                                                unsigned short* __restrict__ E,
                                                float* __restrict__ rowsum) {
    __shared__ __align__(16) char smem[32768];
    uint8_t* As = (uint8_t*)smem;            // [128 rows][128 B] = 16 KB
    uint8_t* Bs = (uint8_t*)(smem + 16384);  // 16 KB

    const int t    = threadIdx.x;
    const int lane = t & 63;
    const int wave = t >> 6;      // 0..7
    const int wm   = wave >> 2;   // 0..1  (64-row strip)
    const int wn   = wave & 3;    // 0..3  (32-col strip)

    // decode triangular block index: b = I*(I+1)/2 + J, J <= I
    const int b = blockIdx.x;
    int I = (int)((sqrtf((float)(8 * b + 1)) - 1.0f) * 0.5f);
    if ((I + 1) * (I + 2) / 2 <= b) ++I;   // fp-safety fixups
    if (I * (I + 1) / 2 > b) --I;
    const int Jb = b - I * (I + 1) / 2;
    const int bm = I * BM;   // row block (>= col block)
    const int bn = Jb * BM;
    const bool diag = (I == Jb);

    floatx4 acc[4][2] = {};

    // staging: slot s = i*512 + t; row = s>>3 (64 rows/issue), 16B-block = s&7,
    // holding global k-block (s&7)^(row&7)  [XOR swizzle, source-side]
    const int srow = t >> 3;                    // 0..63 (+64*i)
    const int skb  = (t & 7) ^ (srow & 7);
    const uint8_t* Ag = X8 + (long)(bm + srow) * N + skb * 16;
    const uint8_t* Bg = X8 + (long)(bn + srow) * N + skb * 16;
    uint8_t* Asl = As + t * 16;
    uint8_t* Bsl = Bs + t * 16;

    for (int k0 = 0; k0 < N; k0 += BK8) {
#pragma unroll
        for (int i = 0; i < 2; ++i) {
            // (srow + 64*i) & 7 == srow & 7: same swizzled offset works
            gld_lds16(Ag + (long)i * 64 * N + k0, Asl + i * 8192);
            gld_lds16(Bg + (long)i * 64 * N + k0, Bsl + i * 8192);
        }
        __syncthreads();

        const int l15 = lane & 15;
        const int l7  = lane & 7;
        const int q   = lane >> 4;
        // A-frag (16x128 tile): lane holds row=l15, k = q*32 .. q*32+31
        // = 16B-blocks 2q, 2q+1 (swizzled slots (2q+se)^l7; row&7==l7 since
        // wm*64, i*16, wn*32 are all multiples of 8/16).
        i32x8 af[4], bfr[2];
#pragma unroll
        for (int i = 0; i < 4; ++i) {
            const int row = wm * 64 + i * 16 + l15;
            i32x4 lo = *(const i32x4*)&As[(row * 8 + ((2 * q) ^ l7)) * 16];
            i32x4 hi = *(const i32x4*)&As[(row * 8 + ((2 * q + 1) ^ l7)) * 16];
            af[i] = (i32x8){lo.x, lo.y, lo.z, lo.w, hi.x, hi.y, hi.z, hi.w};
        }
#pragma unroll
        for (int j = 0; j < 2; ++j) {
            const int row = wn * 32 + j * 16 + l15;
            i32x4 lo = *(const i32x4*)&Bs[(row * 8 + ((2 * q) ^ l7)) * 16];
            i32x4 hi = *(const i32x4*)&Bs[(row * 8 + ((2 * q + 1) ^ l7)) * 16];
            bfr[j] = (i32x8){lo.x, lo.y, lo.z, lo.w, hi.x, hi.y, hi.z, hi.w};
        }
#pragma unroll
        for (int i = 0; i < 4; ++i)
#pragma unroll
            for (int j = 0; j < 2; ++j)
                acc[i][j] = __builtin_amdgcn_mfma_scale_f32_16x16x128_f8f6f4(
                    af[i], bfr[j], acc[i][j],
                    0, 0,               // cbsz=0 (A fp8 e4m3), blgp=0 (B fp8)
                    0, 0x79797979,      // A scale: e8m0 121 = 2^-6, all bytes
                    0, 0x79797979);     // B scale: 2^-6  (product: 1/4096)
        __syncthreads();
    }

    // ---- epilogue: C/D layout col=lane&15, row=(lane>>4)*4+reg ----
    const int l15  = lane & 15;
    const int q    = lane >> 4;
    const int col0 = bn + wn * 32 + l15;
    const int row0 = bm + wm * 64 + q * 4;

#pragma unroll
    for (int i = 0; i < 4; ++i) {
#pragma unroll
        for (int r = 0; r < 4; ++r) {
            const int row = row0 + i * 16 + r;
            float rs = 0.f;
#pragma unroll
            for (int j = 0; j < 2; ++j) {
                const int col = col0 + j * 16;
                // no max-subtraction: sims ~ +-0.3, exp safe; shift cancels.
                float e = (row == col) ? 0.f : __expf(acc[i][j][r]);
                acc[i][j][r] = e;
                rs += e;
                E[(long)row * N + col] = f2bf(e);
            }
#pragma unroll
            for (int off = 1; off < 16; off <<= 1) rs += __shfl_xor(rs, off);
            if (l15 == 0) atomicAdd(rowsum + row, rs);
        }
    }

    if (!diag) {
        // column sums -> row sums of the mirror tile
#pragma unroll
        for (int j = 0; j < 2; ++j) {
            float cs = 0.f;
#pragma unroll
            for (int i = 0; i < 4; ++i)
#pragma unroll
                for (int r = 0; r < 4; ++r) cs += acc[i][j][r];
            cs += __shfl_xor(cs, 16);
            cs += __shfl_xor(cs, 32);
            if (q == 0) atomicAdd(rowsum + bn + wn * 32 + j * 16 + l15, cs);
        }

        // per-wave 32x64 transpose through swizzled LDS (aliases As/Bs)
        unsigned short* tb = (unsigned short*)smem + wave * 2048;  // 4 KB/wave
        __syncthreads();
#pragma unroll
        for (int i = 0; i < 4; ++i) {
            const int lr0 = i * 16 + q * 4;
            const int blk = lr0 >> 3;
            const int half = (lr0 >> 2) & 1;
#pragma unroll
            for (int j = 0; j < 2; ++j) {
                const int lc = j * 16 + l15;
                union { unsigned short u[4]; uint2 v2; } pk;
#pragma unroll
                for (int r = 0; r < 4; ++r) pk.u[r] = f2bf(acc[i][j][r]);
                *(uint2*)&tb[lc * 64 + 8 * (blk ^ (lc & 7)) + 4 * half] = pk.v2;
            }
        }
        __syncthreads();

        const int gr0 = lane >> 3;
        const int cb  = lane & 7;
#pragma unroll
        for (int p = 0; p < 4; ++p) {
            const int gr = p * 8 + gr0;
            uint4 v = *(const uint4*)&tb[gr * 64 + 8 * (cb ^ (gr & 7))];
            *(uint4*)&E[(long)(bn + wn * 32 + gr) * N + bm + wm * 64 + cb * 8] = v;
        }
    }
}

// ---------------------------------------------------------------------------
// Kernel 3 (gemm_pv): out = (E/rowsum) x^T.
// R6: ported from the m97-structure 128^2 (40% MfmaUtil ~= 916 TF, the
// documented ~900 TF ceiling of that structure) to the 256^2 8-phase
// schedule (T3+T4 counted-vmcnt + T5 setprio): 512 thr / 8 waves (2Mx4N),
// 128x64 per-wave tile, PK=64, 128 KiB LDS = 2 dbuf x (A 256x64 + B 256x64),
// raw s_barrier (no __syncthreads vmcnt-drain), vmcnt(4) ONLY at phases 4/8.
// LDS swizzle: this kernel's proven 16B-block XOR (slot b holds global
// k-block b^(row&7)), staged source-side; frag read slot (4ks+q)^l7 ->
// 2-way bank aliasing only (free; measured 0 conflicts R2-R5).
// Stage->read invariants (stage issued only after the barrier following the
// region's last ds_read; each wave's lgkmcnt(0) precedes that barrier):
//   buf0.A read ph1,3  staged ph5,6   | buf0.B read ph1,2  staged ph3,4
//   buf1.A read ph5,7  staged ph1,2   | buf1.B read ph5,6  staged ph7,8
// vmcnt(4) @ph4 end: A(2i+1)h1 landed (ph3+ph4's 4 loads may stay in flight)
// vmcnt(4) @ph8 end: A(2i+2)+B(2i+2) landed (ph7+ph8's 4 loads in flight)
// Last iteration's surplus stages wrap k-offset mod N; they land in regions
// already past their last read and are never consumed (safe, ~48KB/block).
// ---------------------------------------------------------------------------
#define PV_BAR()   __builtin_amdgcn_s_barrier()
#define PV_LGKM0() asm volatile("s_waitcnt lgkmcnt(0)" ::: "memory")
#define PV_VM4()   asm volatile("s_waitcnt vmcnt(4)" ::: "memory")

#define PV_STAGE_A(buf, h, k0) do { \
    const bf16* s_ = Asrc + (h) * 128 * (long)N + (k0); \
    bf16* d_ = dstl + (buf) * 16384 + (h) * 8192; \
    gld_lds16(s_, d_); \
    gld_lds16(s_ + 64 * (long)N, d_ + 4096); } while (0)

#define PV_STAGE_B(buf, h, k0) do { \
    const bf16* s_ = Bsrc + (h) * 128 * (long)N + (k0); \
    bf16* d_ = dstl + 32768 + (buf) * 16384 + (h) * 8192; \
    gld_lds16(s_, d_); \
    gld_lds16(s_ + 64 * (long)N, d_ + 4096); } while (0)

#define PV_LDA(buf, mi) do { \
    const bf16* b_ = lds + (buf) * 16384; \
    _Pragma("unroll") for (int f_ = 0; f_ < 4; ++f_) { \
      const int r_ = wm * 128 + (mi) * 64 + f_ * 16 + l15; \
      ar[f_][0] = *(const bfrag*)&b_[(r_ * 8 + (q ^ l7)) * 8]; \
      ar[f_][1] = *(const bfrag*)&b_[(r_ * 8 + ((4 + q) ^ l7)) * 8]; } } while (0)

#define PV_LDB(buf, nj) do { \
    const bf16* b_ = lds + 32768 + (buf) * 16384; \
    _Pragma("unroll") for (int g_ = 0; g_ < 2; ++g_) { \
      const int r_ = wn * 64 + (nj) * 32 + g_ * 16 + l15; \
      br[nj][g_][0] = *(const bfrag*)&b_[(r_ * 8 + (q ^ l7)) * 8]; \
      br[nj][g_][1] = *(const bfrag*)&b_[(r_ * 8 + ((4 + q) ^ l7)) * 8]; } } while (0)

#define PV_MM(mi, nj) do { \
    __builtin_amdgcn_s_setprio(1); \
    _Pragma("unroll") for (int f_ = 0; f_ < 4; ++f_) \
    _Pragma("unroll") for (int g_ = 0; g_ < 2; ++g_) \
    _Pragma("unroll") for (int k_ = 0; k_ < 2; ++k_) \
      acc[(mi)*4+f_][(nj)*2+g_] = __builtin_amdgcn_mfma_f32_16x16x32_bf16( \
          ar[f_][k_], br[nj][g_][k_], acc[(mi)*4+f_][(nj)*2+g_], 0, 0, 0); \
    __builtin_amdgcn_s_setprio(0); } while (0)

__global__ __launch_bounds__(512, 2) void gemm_pv(const bf16* __restrict__ A,
                                                  const bf16* __restrict__ B,
                                                  float* __restrict__ C,
                                                  const float* __restrict__ rowsum) {
    __shared__ __align__(16) bf16 lds[4 * 16384];  // 128 KiB: A0 A1 B0 B1

    const int t    = threadIdx.x;
    const int lane = t & 63;
    const int wm   = (t >> 6) >> 2;  // 0..1 (128-row strip)
    const int wn   = (t >> 6) & 3;   // 0..3 (64-col strip)
    const int l15  = lane & 15;
    const int l7   = lane & 7;
    const int q    = lane >> 4;

    // bijective XCD swizzle (256 blocks % 8 XCDs == 0): each XCD owns two
    // full 256-row block-rows -> A-panel L2 reuse.
    const int swz = (blockIdx.x & 7) * 32 + (blockIdx.x >> 3);
    const int bm  = (swz >> 4) * PM;
    const int bn  = (swz & 15) * PN;

    // staging: slot s=t covers row srow (64 rows/issue), 16B-block t&7
    // holding global k-block (t&7)^(srow&7)  [source-side XOR swizzle]
    const int srow = t >> 3;
    const int skb  = (t & 7) ^ (srow & 7);
    const bf16* Asrc = A + (long)(bm + srow) * N + skb * 8;
    const bf16* Bsrc = B + (long)(bn + srow) * N + skb * 8;
    bf16* dstl = lds + t * 8;

    floatx4 acc[8][4] = {};
    bfrag ar[4][2], br[2][2][2];

    // prologue: B(0),A(0) -> buf0; B(1) -> buf1.  A(1) staged in ph1/2.
    PV_STAGE_B(0, 0, 0); PV_STAGE_B(0, 1, 0);
    PV_STAGE_A(0, 0, 0); PV_STAGE_A(0, 1, 0);
    PV_STAGE_B(1, 0, PK); PV_STAGE_B(1, 1, PK);
    PV_VM4();  // B(0)+A(0) landed; B(1)'s 4 loads stay in flight
    PV_BAR();

    for (int i = 0; i < 32; ++i) {
        const int ka1 = ((2 * i + 1) * PK) & (N - 1);
        const int kb2 = ((2 * i + 2) * PK) & (N - 1);  // also A(2i+2) offset
        const int kb3 = ((2 * i + 3) * PK) & (N - 1);
        // ph1: K-tile 2i, quadrant (mi0,nj0)     [12 ds_read_b128]
        PV_LDA(0, 0); PV_LDB(0, 0); PV_STAGE_A(1, 0, ka1);
        PV_BAR(); PV_LGKM0();
        PV_MM(0, 0);
        PV_BAR();
        // ph2: (mi0,nj1)                          [4 ds_read]
        PV_LDB(0, 1); PV_STAGE_A(1, 1, ka1);
        PV_BAR(); PV_LGKM0();
        PV_MM(0, 1);
        PV_BAR();
        // ph3: (mi1,nj1)                          [8 ds_read]
        PV_LDA(0, 1); PV_STAGE_B(0, 0, kb2);
        PV_BAR(); PV_LGKM0();
        PV_MM(1, 1);
        PV_BAR();
        // ph4: (mi1,nj0) -- regs only; counted wait for A(2i+1) before BAR2
        PV_STAGE_B(0, 1, kb2);
        PV_BAR();
        PV_MM(1, 0);
        PV_VM4(); PV_BAR();
        // ph5: K-tile 2i+1, (mi0,nj0)             [12 ds_read]
        PV_LDA(1, 0); PV_LDB(1, 0); PV_STAGE_A(0, 0, kb2);
        PV_BAR(); PV_LGKM0();
        PV_MM(0, 0);
        PV_BAR();
        // ph6: (mi0,nj1)
        PV_LDB(1, 1); PV_STAGE_A(0, 1, kb2);
        PV_BAR(); PV_LGKM0();
        PV_MM(0, 1);
        PV_BAR();
        // ph7: (mi1,nj1)
        PV_LDA(1, 1); PV_STAGE_B(1, 0, kb3);
        PV_BAR(); PV_LGKM0();
        PV_MM(1, 1);
        PV_BAR();
        // ph8: (mi1,nj0); counted wait for tile 2i+2 before BAR2
        PV_STAGE_B(1, 1, kb3);
        PV_BAR();
        PV_MM(1, 0);
        PV_VM4(); PV_BAR();
    }

    // epilogue: C/D layout col=lane&15, row=q*4+reg; fuse 1/rowsum
    const int rowbase = bm + wm * 128 + q * 4;
    const int colbase = bn + wn * 64 + l15;
#pragma unroll
    for (int f = 0; f < 8; ++f) {
#pragma unroll
        for (int r = 0; r < 4; ++r) {
            const int row = rowbase + f * 16 + r;
            const float inv = 1.0f / rowsum[row];
#pragma unroll
            for (int g = 0; g < 4; ++g)
                C[(long)row * N + colbase + g * 16] = acc[f][g][r] * inv;
        }
    }
}

// ---------------------------------------------------------------------------
extern "C" void kernel_launch(void* const* d_in, const int* in_sizes, int n_in,
                              void* d_out, int out_size, void* d_ws, size_t ws_size,
                              hipStream_t stream) {
    const float* in = (const float*)d_in[0];
    float* out = (float*)d_out;

    // ws layout: [rowsum 16KB] [xb 32MB bf16] [E 32MB bf16].
    // x8 (16MB fp8) lives in d_out's first 16MB -- dead until gemm_pv's
    // final write, which happens after gemm_sym has consumed x8.
    float* rowsum = (float*)d_ws;
    bf16* xb = (bf16*)((char*)d_ws + 16384);
    unsigned short* E = (unsigned short*)((char*)d_ws + 16384 + (size_t)N * N * sizeof(bf16));
    uint8_t* x8 = (uint8_t*)d_out;

    cvt_scale<<<(N * (long)N) / (256 * 8), 256, 0, stream>>>(
        in, (unsigned short*)xb, x8, rowsum);

    // E = exp(mask(x x^T)) via 528 triangular fp8 tiles (32 K-iterations)
    gemm_sym<<<528, 512, 0, stream>>>(x8, E, rowsum);
    // out = (E / rowsum) x^T  -- 256^2 8-phase, 256 blocks (1/CU)
    gemm_pv<<<256, 512, 0, stream>>>((const bf16*)E, xb, out, rowsum);
}